// Round 9
// baseline (229.494 us; speedup 1.0000x reference)
//
#include <hip/hip_runtime.h>
#include <cstdint>

// ---------- types ----------
using bx8 = __attribute__((ext_vector_type(8))) __bf16;   // MFMA A/B fragment (8 bf16)
using us8 = __attribute__((ext_vector_type(8))) unsigned short;
using fx4 = __attribute__((ext_vector_type(4))) float;    // MFMA C/D fragment

static __device__ inline unsigned short f2bf(float f) {
  unsigned u = __builtin_bit_cast(unsigned, f);
  unsigned r = 0x7FFFu + ((u >> 16) & 1u);   // round-to-nearest-even
  return (unsigned short)((u + r) >> 16);
}
static __device__ inline float bf2f(unsigned short s) {
  return __builtin_bit_cast(float, (unsigned)s << 16);
}

static __device__ inline fx4 mfma16(bx8 a, bx8 b, fx4 c) {
  return __builtin_amdgcn_mfma_f32_16x16x32_bf16(a, b, c, 0, 0, 0);
}

// async global->LDS, 16B/lane. LDS dest = wave-uniform base + lane*16.
static __device__ inline void gload16(const void* g, void* lds) {
  __builtin_amdgcn_global_load_lds(
      (const __attribute__((address_space(1))) void*)g,
      (__attribute__((address_space(3))) void*)lds,
      16, 0, 0);
}
// Explicit drain: do NOT trust __syncthreads() to wait for global_load_lds
// on this toolchain (prime suspect for the R1/R2 deterministic garbage).
static __device__ inline void drain_vmem() {
  asm volatile("s_waitcnt vmcnt(0)" ::: "memory");
}

// DPP row_ror:k (VALU-latency cross-lane, not the ~120cy LDS-pipe shfl path).
#define DPP_ROR(x, k) __builtin_bit_cast(float, __builtin_amdgcn_update_dpp( \
    __builtin_bit_cast(int, x), __builtin_bit_cast(int, x), 0x120 | (k), 0xF, 0xF, false))

static __device__ inline float rowmax16(float v) {
  v = fmaxf(v, DPP_ROR(v, 1));
  v = fmaxf(v, DPP_ROR(v, 2));
  v = fmaxf(v, DPP_ROR(v, 4));
  v = fmaxf(v, DPP_ROR(v, 8));
  return v;
}
static __device__ inline float rowsum16(float v) {
  v += DPP_ROR(v, 1);
  v += DPP_ROR(v, 2);
  v += DPP_ROR(v, 4);
  v += DPP_ROR(v, 8);
  return v;
}

// ---------- fp32 -> bf16 convert (R4-proven) ----------
__global__ __launch_bounds__(256) void f2b_kernel(const float* __restrict__ in,
                                                  unsigned short* __restrict__ out,
                                                  int n) {
  int i = (blockIdx.x * 256 + threadIdx.x) * 4;
  if (i >= n) return;
  float4 v = *reinterpret_cast<const float4*>(in + i);
  ushort4 o;
  o.x = f2bf(v.x); o.y = f2bf(v.y); o.z = f2bf(v.z); o.w = f2bf(v.w);
  *reinterpret_cast<ushort4*>(out + i) = o;
}

// ---------- bf16 GEMM, C[M,N] = A[M,K] * B[N,K]^T (row-major, K-major) ----------
// m97-exact structure: 128x128 tile, BK=64, 4 waves (2x2), global_load_lds
// width 16, linear LDS, 2-barrier K-loop, EXPLICIT vmcnt(0) drain.
template <bool F32OUT>
__global__ __launch_bounds__(256) void gemm_bt(const unsigned short* __restrict__ A,
                                               const unsigned short* __restrict__ B,
                                               void* __restrict__ Cp,
                                               int M, int N, int K) {
  __shared__ alignas(16) unsigned short As[128 * 64];
  __shared__ alignas(16) unsigned short Bs[128 * 64];
  const int tid = threadIdx.x;
  const int w = tid >> 6, l = tid & 63;
  const int l16 = l & 15, lg = l >> 4;
  const int wr = w >> 1, wc = w & 1;
  const long mb = (long)blockIdx.y * 128, nb = (long)blockIdx.x * 128;

  const fx4 fz = {0.f, 0.f, 0.f, 0.f};
  fx4 acc[4][4];
#pragma unroll
  for (int i = 0; i < 4; ++i)
#pragma unroll
    for (int j = 0; j < 4; ++j) acc[i][j] = fz;

  const int srow = l >> 3;        // 0..7  (8 lanes per 128B row)
  const int scol = (l & 7) * 8;   // element offset within row

  for (int k0 = 0; k0 < K; k0 += 64) {
    __syncthreads();  // prior iter's LDS reads done
#pragma unroll
    for (int i = 0; i < 4; ++i) {
      const int rb = w * 32 + i * 8;
      gload16(A + (mb + rb + srow) * (long)K + k0 + scol, (char*)As + rb * 128);
      gload16(B + (nb + rb + srow) * (long)K + k0 + scol, (char*)Bs + rb * 128);
    }
    drain_vmem();     // explicit: all gload16 data landed in LDS
    __syncthreads();  // tiles resident for every wave
#pragma unroll
    for (int kk = 0; kk < 2; ++kk) {
      bx8 a[4], b[4];
#pragma unroll
      for (int mf = 0; mf < 4; ++mf)
        a[mf] = *reinterpret_cast<const bx8*>(&As[(wr * 64 + mf * 16 + l16) * 64 + kk * 32 + lg * 8]);
#pragma unroll
      for (int nf = 0; nf < 4; ++nf)
        b[nf] = *reinterpret_cast<const bx8*>(&Bs[(wc * 64 + nf * 16 + l16) * 64 + kk * 32 + lg * 8]);
#pragma unroll
      for (int mf = 0; mf < 4; ++mf)
#pragma unroll
        for (int nf = 0; nf < 4; ++nf)
          acc[mf][nf] = mfma16(a[mf], b[nf], acc[mf][nf]);
    }
  }

  // epilogue: C/D layout col = lane&15, row = (lane>>4)*4 + reg  [m89-verified]
#pragma unroll
  for (int mf = 0; mf < 4; ++mf)
#pragma unroll
    for (int nf = 0; nf < 4; ++nf)
#pragma unroll
      for (int r = 0; r < 4; ++r) {
        const long row = mb + wr * 64 + mf * 16 + lg * 4 + r;
        const long col = nb + wc * 64 + nf * 16 + l16;
        if (F32OUT)
          ((float*)Cp)[row * N + col] = acc[mf][nf][r];
        else
          ((unsigned short*)Cp)[row * N + col] = f2bf(acc[mf][nf][r]);
      }
}

// ---------- flash attention (causal), split-kv (R7-proven, unchanged) ----------
// 768 blocks, one item each, ALL co-resident (3 blocks/CU by LDS).
//   id <  512: two-chunk partials: p=id>>1 (qt=31-(p>>4), h=p&15), c=id&1.
//   id >= 512: singles qt=15-(s>>4): full range, writes attnb directly.
// qkv layout: [T][3C], q at col h*128, k at C + h*128, v at 2C + h*128.
__global__ __launch_bounds__(256) void fa_kernel(const unsigned short* __restrict__ qkv,
                                                 unsigned short* __restrict__ out,
                                                 unsigned short* __restrict__ Obuf,
                                                 float* __restrict__ ML) {
  __shared__ alignas(16) unsigned short Ks[64 * 136];      // K-tile, padded stride 136
  __shared__ alignas(16) unsigned short Vt[128 * 72];      // V^T, padded stride 72
  __shared__ alignas(16) unsigned short Ps[4][16 * 72];    // per-wave P buffer

  const int id = blockIdx.x;
  int h, qt, t0, t1;
  bool partial;
  if (id < 512) {
    const int p = id >> 1, c = id & 1;
    qt = 31 - (p >> 4); h = p & 15;
    const int nt0 = (qt + 2) >> 1;       // balanced split of qt+1 tiles
    t0 = c ? nt0 : 0;
    t1 = c ? (qt + 1) : nt0;
    partial = true;
  } else {
    const int s = id - 512;
    qt = 15 - (s >> 4); h = s & 15;
    t0 = 0; t1 = qt + 1;
    partial = false;
  }
  const int qb = qt * 64;

  const int tid = threadIdx.x;
  const int w = tid >> 6, l = tid & 63;
  const int l16 = l & 15, lg = l >> 4;
  const fx4 fz = {0.f, 0.f, 0.f, 0.f};

  // staging coordinates
  const int kr = tid >> 4, kc8 = (tid & 15) * 8;   // K-stage coords
  const int kv = tid & 63, d0v = (tid >> 6) * 32;  // V-stage coords

  // Q fragments in registers: A-frag row = l&15, k = (l>>4)*8 + j
  bx8 qf[4];
  {
    const long qrow = qb + w * 16 + l16;
    const unsigned short* qp = qkv + qrow * 6144L + h * 128 + lg * 8;
#pragma unroll
    for (int kc = 0; kc < 4; ++kc)
      qf[kc] = *reinterpret_cast<const bx8*>(qp + kc * 32);
  }

  fx4 o_acc[8];
#pragma unroll
  for (int i = 0; i < 8; ++i) o_acc[i] = fz;
  float m_r[4] = {-3e38f, -3e38f, -3e38f, -3e38f};
  float l_r[4] = {0.f, 0.f, 0.f, 0.f};

  // prologue: load tile t0 into staging regs
  us8 rK[4], rV[4];
  {
    const long kvb = (long)t0 * 64;
#pragma unroll
    for (int p = 0; p < 4; ++p)
      rK[p] = *reinterpret_cast<const us8*>(qkv + (kvb + p * 16 + kr) * 6144L + 2048 + h * 128 + kc8);
#pragma unroll
    for (int i = 0; i < 4; ++i)
      rV[i] = *reinterpret_cast<const us8*>(qkv + (kvb + kv) * 6144L + 4096 + h * 128 + d0v + i * 8);
  }

  for (int t = t0; t < t1; ++t) {
    __syncthreads();  // all waves done with previous LDS tile

    // write staged regs (tile t) to LDS
#pragma unroll
    for (int p = 0; p < 4; ++p)
      *reinterpret_cast<us8*>(&Ks[(p * 16 + kr) * 136 + kc8]) = rK[p];
#pragma unroll
    for (int i = 0; i < 4; ++i)
#pragma unroll
      for (int j = 0; j < 8; ++j)
        Vt[(d0v + i * 8 + j) * 72 + kv] = rV[i][j];

    // issue loads for tile t+1 (land during compute below)
    if (t + 1 < t1) {
      const long kvb = (long)(t + 1) * 64;
#pragma unroll
      for (int p = 0; p < 4; ++p)
        rK[p] = *reinterpret_cast<const us8*>(qkv + (kvb + p * 16 + kr) * 6144L + 2048 + h * 128 + kc8);
#pragma unroll
      for (int i = 0; i < 4; ++i)
        rV[i] = *reinterpret_cast<const us8*>(qkv + (kvb + kv) * 6144L + 4096 + h * 128 + d0v + i * 8);
    }
    __syncthreads();  // K and V resident in LDS

    // --- S = Q * K^T  (16 q x 64 kv per wave) ---
    fx4 s[4];
#pragma unroll
    for (int nf = 0; nf < 4; ++nf) s[nf] = fz;
#pragma unroll
    for (int kc = 0; kc < 4; ++kc) {
#pragma unroll
      for (int nf = 0; nf < 4; ++nf) {
        const int rl = nf * 16 + l16;
        bx8 kb = *reinterpret_cast<const bx8*>(&Ks[rl * 136 + kc * 32 + lg * 8]);
        s[nf] = mfma16(qf[kc], kb, s[nf]);
      }
    }

    // --- causal mask (possible only on tile t == qt) ---
    if (t == qt) {
#pragma unroll
      for (int nf = 0; nf < 4; ++nf) {
        const int kv_abs = t * 64 + nf * 16 + l16;
#pragma unroll
        for (int r = 0; r < 4; ++r) {
          const int q_abs = qb + w * 16 + lg * 4 + r;
          if (kv_abs > q_abs) s[nf][r] = -3e38f;
        }
      }
    }

    // --- online softmax (exp2; scale*log2e folded) ---
    const float sc2 = 0.1275173831f;  // (1/sqrt(128)) * log2(e)
    float pv[4][4];
#pragma unroll
    for (int r = 0; r < 4; ++r) {
      float rm = fmaxf(fmaxf(s[0][r], s[1][r]), fmaxf(s[2][r], s[3][r]));
      rm = rowmax16(rm);
      const float mn = fmaxf(m_r[r], rm);
      const float fac = exp2f((m_r[r] - mn) * sc2);
      m_r[r] = mn;
      float rs = 0.f;
#pragma unroll
      for (int nf = 0; nf < 4; ++nf) {
        const float p = exp2f((s[nf][r] - mn) * sc2);
        pv[nf][r] = p;
        rs += p;
      }
      rs = rowsum16(rs);
      l_r[r] = l_r[r] * fac + rs;
#pragma unroll
      for (int nf = 0; nf < 8; ++nf) o_acc[nf][r] *= fac;
    }

    // --- P -> per-wave LDS -> A-fragments ---
    unsigned short* psw = &Ps[w][0];
#pragma unroll
    for (int nf = 0; nf < 4; ++nf)
#pragma unroll
      for (int r = 0; r < 4; ++r)
        psw[(lg * 4 + r) * 72 + nf * 16 + l16] = f2bf(pv[nf][r]);

    bx8 pa[2];
#pragma unroll
    for (int kc = 0; kc < 2; ++kc)
      pa[kc] = *reinterpret_cast<const bx8*>(&psw[l16 * 72 + kc * 32 + lg * 8]);

    // --- O += P * V ---
#pragma unroll
    for (int nf = 0; nf < 8; ++nf) {
#pragma unroll
      for (int kc = 0; kc < 2; ++kc) {
        bx8 vb = *reinterpret_cast<const bx8*>(&Vt[(nf * 16 + l16) * 72 + kc * 32 + lg * 8]);
        o_acc[nf] = mfma16(pa[kc], vb, o_acc[nf]);
      }
    }
  }

  if (!partial) {
    // direct write O / l to attn_out[T][C], col = h*128 + d
#pragma unroll
    for (int nf = 0; nf < 8; ++nf)
#pragma unroll
      for (int r = 0; r < 4; ++r) {
        const long row = qb + w * 16 + lg * 4 + r;
        const long col = h * 128 + nf * 16 + l16;
        out[row * 2048 + col] = f2bf(o_acc[nf][r] / l_r[r]);
      }
  } else {
    // write O-numerator (bf16) + per-row (m, l) partials
    unsigned short* ob = Obuf + (long)id * 8192;
#pragma unroll
    for (int nf = 0; nf < 8; ++nf)
#pragma unroll
      for (int r = 0; r < 4; ++r) {
        const int row = w * 16 + lg * 4 + r;
        ob[row * 128 + nf * 16 + l16] = f2bf(o_acc[nf][r]);
      }
    if (l16 == 0) {
#pragma unroll
      for (int r = 0; r < 4; ++r) {
        const int row = w * 16 + lg * 4 + r;
        ML[((long)id * 64 + row) * 2 + 0] = m_r[r];
        ML[((long)id * 64 + row) * 2 + 1] = l_r[r];
      }
    }
  }
}

// ---------- combine two kv-chunk partials into attnb (R7-proven, unchanged) ----------
__global__ __launch_bounds__(256) void fa_combine(const unsigned short* __restrict__ Obuf,
                                                  const float* __restrict__ ML,
                                                  unsigned short* __restrict__ out) {
  const int p = blockIdx.x;
  const int qt = 31 - (p >> 4), h = p & 15;
  const int tid = threadIdx.x;
  const int row = tid >> 2;            // 0..63
  const int c0 = (tid & 3) * 32;       // col base, 32 cols per thread

  const long idA = 2 * p, idB = 2 * p + 1;
  const float mA = ML[(idA * 64 + row) * 2 + 0];
  const float lA = ML[(idA * 64 + row) * 2 + 1];
  const float mB = ML[(idB * 64 + row) * 2 + 0];
  const float lB = ML[(idB * 64 + row) * 2 + 1];
  const float sc2 = 0.1275173831f;
  const float m = fmaxf(mA, mB);
  const float fA = exp2f((mA - m) * sc2);
  const float fB = exp2f((mB - m) * sc2);
  const float inv = 1.0f / (lA * fA + lB * fB);
  const float cA = fA * inv, cB = fB * inv;

  const unsigned short* oa = Obuf + idA * 8192 + row * 128 + c0;
  const unsigned short* obp = Obuf + idB * 8192 + row * 128 + c0;
  unsigned short* dst = out + (long)(qt * 64 + row) * 2048 + h * 128 + c0;
#pragma unroll
  for (int j = 0; j < 4; ++j) {
    us8 a = *reinterpret_cast<const us8*>(oa + j * 8);
    us8 b = *reinterpret_cast<const us8*>(obp + j * 8);
    ushort4 o0, o1;
    float v0, v1, v2, v3;
    v0 = bf2f(a[0]) * cA + bf2f(b[0]) * cB;
    v1 = bf2f(a[1]) * cA + bf2f(b[1]) * cB;
    v2 = bf2f(a[2]) * cA + bf2f(b[2]) * cB;
    v3 = bf2f(a[3]) * cA + bf2f(b[3]) * cB;
    o0 = {f2bf(v0), f2bf(v1), f2bf(v2), f2bf(v3)};
    v0 = bf2f(a[4]) * cA + bf2f(b[4]) * cB;
    v1 = bf2f(a[5]) * cA + bf2f(b[5]) * cB;
    v2 = bf2f(a[6]) * cA + bf2f(b[6]) * cB;
    v3 = bf2f(a[7]) * cA + bf2f(b[7]) * cB;
    o1 = {f2bf(v0), f2bf(v1), f2bf(v2), f2bf(v3)};
    *reinterpret_cast<ushort4*>(dst + j * 8) = o0;
    *reinterpret_cast<ushort4*>(dst + j * 8 + 4) = o1;
  }
}

// ---------- launch ----------
// Interface (confirmed R4): inputs fp32, output fp32.
// Workspace plan (R4/R7-proven overlays, peak 56 MiB):
//   wab   [0, 24 MiB)     bf16 W_attn (dead after GEMM1)
//   qkvb  [24, 48 MiB)    bf16 qkv
//   xb    [48, 56 MiB)    bf16 x (dead after GEMM1)
//   -- after GEMM1, overlaying dead regions:
//   Obuf  [0, 8 MiB)      512 x 64x128 bf16 partial O numerators
//   ML    [8, 8.25 MiB)   512 x 64 x (m,l) fp32
//   wpb   [9, 17 MiB)     bf16 W_proj
//   attnb [48, 56 MiB)    bf16 attn out (overlays dead xb)
extern "C" void kernel_launch(void* const* d_in, const int* in_sizes, int n_in,
                              void* d_out, int out_size, void* d_ws, size_t ws_size,
                              hipStream_t stream) {
  const float* x  = (const float*)d_in[0];   // (2048, 2048) fp32
  const float* Wa = (const float*)d_in[1];   // (6144, 2048) fp32
  const float* Wp = (const float*)d_in[2];   // (2048, 2048) fp32
  float* out = (float*)d_out;                // (2048, 2048) fp32
  char* ws = (char*)d_ws;

  unsigned short* wab   = (unsigned short*)(ws);                 // 24 MiB
  unsigned short* qkvb  = (unsigned short*)(ws + (24ull << 20)); // 24 MiB
  unsigned short* xb    = (unsigned short*)(ws + (48ull << 20)); //  8 MiB
  unsigned short* Obuf  = (unsigned short*)(ws);                 //  8 MiB (after GEMM1)
  float*          ML    = (float*)(ws + (8ull << 20));           // 256 KiB (after GEMM1)
  unsigned short* wpb   = (unsigned short*)(ws + (9ull << 20));  //  8 MiB (after GEMM1)
  unsigned short* attnb = (unsigned short*)(ws + (48ull << 20)); //  8 MiB (after GEMM1)

  f2b_kernel<<<4096, 256, 0, stream>>>(x, xb, 2048 * 2048);
  f2b_kernel<<<12288, 256, 0, stream>>>(Wa, wab, 6144 * 2048);

  // qkv = x @ W_attn^T : M=2048, N=6144, K=2048 (global_load_lds + explicit drain)
  gemm_bt<false><<<dim3(48, 16), 256, 0, stream>>>(xb, wab, (void*)qkvb, 2048, 6144, 2048);

  // W_proj convert into region freed by wab (stream-ordered after GEMM1)
  f2b_kernel<<<4096, 256, 0, stream>>>(Wp, wpb, 2048 * 2048);

  // causal flash attention, split-kv: 768 one-item blocks, all co-resident
  fa_kernel<<<768, 256, 0, stream>>>(qkvb, attnb, Obuf, ML);

  // merge two-chunk partials (qt >= 16)
  fa_combine<<<256, 256, 0, stream>>>(Obuf, ML, attnb);

  // out = attn @ W_proj^T : M=2048, N=2048, K=2048, fp32 out
  gemm_bt<true><<<dim3(16, 16), 256, 0, stream>>>(attnb, wpb, (void*)out, 2048, 2048, 2048);
}

// Round 10
// 180.033 us; speedup vs baseline: 1.2747x; 1.2747x over previous
//
#include <hip/hip_runtime.h>
#include <cstdint>

// ---------- types ----------
using bx8 = __attribute__((ext_vector_type(8))) __bf16;   // MFMA A/B fragment (8 bf16)
using us8 = __attribute__((ext_vector_type(8))) unsigned short;
using fl8 = __attribute__((ext_vector_type(8))) float;
using fx4 = __attribute__((ext_vector_type(4))) float;    // MFMA C/D fragment

static __device__ inline unsigned short f2bf(float f) {
  unsigned u = __builtin_bit_cast(unsigned, f);
  unsigned r = 0x7FFFu + ((u >> 16) & 1u);   // round-to-nearest-even
  return (unsigned short)((u + r) >> 16);
}
static __device__ inline float bf2f(unsigned short s) {
  return __builtin_bit_cast(float, (unsigned)s << 16);
}

static __device__ inline fx4 mfma16(bx8 a, bx8 b, fx4 c) {
  return __builtin_amdgcn_mfma_f32_16x16x32_bf16(a, b, c, 0, 0, 0);
}

// async global->LDS, 16B/lane; dest = wave-uniform base + lane*16 (R9-proven w/ drain)
static __device__ inline void gload16(const void* g, void* lds) {
  __builtin_amdgcn_global_load_lds(
      (const __attribute__((address_space(1))) void*)g,
      (__attribute__((address_space(3))) void*)lds,
      16, 0, 0);
}
#define VMCNT(n) asm volatile("s_waitcnt vmcnt(" #n ")" ::: "memory")
// raw barrier (does NOT drain vmcnt, unlike __syncthreads) + compiler fences
static __device__ inline void wave_barrier() {
  __builtin_amdgcn_sched_barrier(0);
  __builtin_amdgcn_s_barrier();
  __builtin_amdgcn_sched_barrier(0);
}

// DPP row_ror:k (VALU-latency cross-lane)
#define DPP_ROR(x, k) __builtin_bit_cast(float, __builtin_amdgcn_update_dpp( \
    __builtin_bit_cast(int, x), __builtin_bit_cast(int, x), 0x120 | (k), 0xF, 0xF, false))

static __device__ inline float rowmax16(float v) {
  v = fmaxf(v, DPP_ROR(v, 1));
  v = fmaxf(v, DPP_ROR(v, 2));
  v = fmaxf(v, DPP_ROR(v, 4));
  v = fmaxf(v, DPP_ROR(v, 8));
  return v;
}
static __device__ inline float rowsum16(float v) {
  v += DPP_ROR(v, 1);
  v += DPP_ROR(v, 2);
  v += DPP_ROR(v, 4);
  v += DPP_ROR(v, 8);
  return v;
}

// ---------- fp32 -> bf16 convert (R4-proven) ----------
__global__ __launch_bounds__(256) void f2b_kernel(const float* __restrict__ in,
                                                  unsigned short* __restrict__ out,
                                                  int n) {
  int i = (blockIdx.x * 256 + threadIdx.x) * 4;
  if (i >= n) return;
  float4 v = *reinterpret_cast<const float4*>(in + i);
  ushort4 o;
  o.x = f2bf(v.x); o.y = f2bf(v.y); o.z = f2bf(v.z); o.w = f2bf(v.w);
  *reinterpret_cast<ushort4*>(out + i) = o;
}

// ================= GEMM1: 256x256 tile, BK=32, depth-3 counted-vmcnt pipeline =================
// C[M,N] = A[M,K] * B[N,K]^T (bf16, K-major). 8 waves (2M x 4N), per-wave out 128x64.
// LDS: 4 buffers x (A 16KB + B 16KB) = 128 KiB. global_load_lds w/ pre-swizzled SOURCE
// (slot s of row r holds global col ((s^(r&3))*8)); reads use matching XOR. Raw barriers;
// vmcnt never drained to 0 in steady state (T3+T4); setprio around MFMA (T5).
__global__ __launch_bounds__(512, 2) void gemm256(const unsigned short* __restrict__ A,
                                                  const unsigned short* __restrict__ B,
                                                  unsigned short* __restrict__ C,
                                                  int M, int N, int K) {
  __shared__ unsigned short lds[4][2][256 * 32];   // [buf][A/B][row*32 + col]

  const int tid = threadIdx.x;
  const int w = tid >> 6, l = tid & 63;
  const int l16 = l & 15, lg = l >> 4;
  const int wr = w >> 2, wc = w & 3;
  const long mb = (long)blockIdx.y * 256, nb = (long)blockIdx.x * 256;

  // staging lane constants: chunk = 16 rows x 64B; lane l -> row lr=l>>2, slot l&3
  const int lr = l >> 2;
  const int sw = (((l & 3) ^ (lr & 3)) * 8);       // pre-swizzled col (elements)
  const unsigned short* Ag = A + (mb + w * 32 + lr) * (long)K + sw;
  const unsigned short* Bg = B + (nb + w * 32 + lr) * (long)K + sw;

  // read lane constant: byte col within 64B row, matching the write swizzle
  const int rdcol = ((lg ^ (l16 & 3)) * 16);

  const fx4 fz = {0.f, 0.f, 0.f, 0.f};
  fx4 acc[8][4];
#pragma unroll
  for (int i = 0; i < 8; ++i)
#pragma unroll
    for (int j = 0; j < 4; ++j) acc[i][j] = fz;

  const int nt = K >> 5;   // K/32 tiles

  auto stage = [&](int tp) {
    const int db = tp & 3;
    const unsigned short* as = Ag + tp * 32;
    const unsigned short* bs = Bg + tp * 32;
    char* al = (char*)&lds[db][0][0] + w * 32 * 64;
    char* bl = (char*)&lds[db][1][0] + w * 32 * 64;
    gload16(as, al);
    gload16(as + 16 * (long)K, al + 1024);
    gload16(bs, bl);
    gload16(bs + 16 * (long)K, bl + 1024);
  };

  auto compute = [&](int bt) {
    const char* Ab = (const char*)&lds[bt][0][0] + (wr * 128 + l16) * 64 + rdcol;
    const char* Bb = (const char*)&lds[bt][1][0] + (wc * 64 + l16) * 64 + rdcol;
    bx8 bf[4];
#pragma unroll
    for (int nf = 0; nf < 4; ++nf)
      bf[nf] = *reinterpret_cast<const bx8*>(Bb + nf * 1024);
    __builtin_amdgcn_s_setprio(1);
#pragma unroll
    for (int mf = 0; mf < 8; ++mf) {
      bx8 av = *reinterpret_cast<const bx8*>(Ab + mf * 1024);
#pragma unroll
      for (int nf = 0; nf < 4; ++nf)
        acc[mf][nf] = mfma16(av, bf[nf], acc[mf][nf]);
    }
    __builtin_amdgcn_s_setprio(0);
  };

  // prologue: 3 tiles in flight; wait tile0 (12 outstanding -> 8)
  stage(0); stage(1); stage(2);
  VMCNT(8);
  wave_barrier();

  int t = 0;
  for (; t < nt - 3; ++t) {
    stage(t + 3);        // 4 issues -> 12 outstanding
    compute(t & 3);
    VMCNT(8);            // retire tile t+1's 4 loads
    wave_barrier();
  }
  compute(t & 3); VMCNT(4); wave_barrier(); ++t;   // t = nt-3
  compute(t & 3); VMCNT(0); wave_barrier(); ++t;   // t = nt-2
  compute(t & 3);                                  // t = nt-1

  // epilogue: C/D layout col = lane&15, row = (lane>>4)*4 + reg  [m89-verified]
#pragma unroll
  for (int mf = 0; mf < 8; ++mf)
#pragma unroll
    for (int nf = 0; nf < 4; ++nf)
#pragma unroll
      for (int r = 0; r < 4; ++r) {
        const long row = mb + wr * 128 + mf * 16 + lg * 4 + r;
        const long col = nb + wc * 64 + nf * 16 + l16;
        C[row * N + col] = f2bf(acc[mf][nf][r]);
      }
}

// ---------- staging-reg type per operand dtype (R8-proven fold GEMM) ----------
template <typename T> struct RegOf { using type = us8; };
template <> struct RegOf<float>  { using type = fl8; };

template <typename T>
static __device__ inline typename RegOf<T>::type load8(const T* p) {
  return *reinterpret_cast<const typename RegOf<T>::type*>(p);
}
static __device__ inline us8 toBf(us8 v) { return v; }
static __device__ inline us8 toBf(fl8 f) {
  us8 o;
#pragma unroll
  for (int j = 0; j < 8; ++j) {
    __bf16 b = (__bf16)f[j];
    o[j] = __builtin_bit_cast(unsigned short, b);
  }
  return o;
}

// ---------- GEMM2: R8-proven 128x128 reg-staged fold kernel ----------
template <typename TA, typename TB, bool F32OUT>
__global__ __launch_bounds__(256) void gemm_bt(const TA* __restrict__ A,
                                               const TB* __restrict__ B,
                                               void* __restrict__ Cp,
                                               int M, int N, int K) {
  __shared__ alignas(16) unsigned short As[128 * 64];
  __shared__ alignas(16) unsigned short Bs[128 * 64];
  const int tid = threadIdx.x;
  const int w = tid >> 6, l = tid & 63;
  const int l16 = l & 15, lg = l >> 4;
  const int wr = w >> 1, wc = w & 1;
  const long mb = (long)blockIdx.y * 128, nb = (long)blockIdx.x * 128;

  const fx4 fz = {0.f, 0.f, 0.f, 0.f};
  fx4 acc[4][4];
#pragma unroll
  for (int i = 0; i < 4; ++i)
#pragma unroll
    for (int j = 0; j < 4; ++j) acc[i][j] = fz;

  const int sr  = tid >> 3;        // 0..31
  const int sc8 = (tid & 7) * 8;   // col offset (elements)
  const int wbc = sc8 * 2;         // col offset (bytes)

  typename RegOf<TA>::type rA[4];
  typename RegOf<TB>::type rB[4];

#pragma unroll
  for (int p = 0; p < 4; ++p) {
    const int row = p * 32 + sr;
    rA[p] = load8(A + (mb + row) * (long)K + sc8);
    rB[p] = load8(B + (nb + row) * (long)K + sc8);
  }

  for (int k0 = 0; k0 < K; k0 += 64) {
    __syncthreads();
#pragma unroll
    for (int p = 0; p < 4; ++p) {
      const int row = p * 32 + sr;
      const int eo = row * 64 + ((wbc ^ ((row & 7) << 4)) >> 1);
      *reinterpret_cast<us8*>(&As[eo]) = toBf(rA[p]);
      *reinterpret_cast<us8*>(&Bs[eo]) = toBf(rB[p]);
    }
    if (k0 + 64 < K) {
#pragma unroll
      for (int p = 0; p < 4; ++p) {
        const int row = p * 32 + sr;
        rA[p] = load8(A + (mb + row) * (long)K + k0 + 64 + sc8);
        rB[p] = load8(B + (nb + row) * (long)K + k0 + 64 + sc8);
      }
    }
    __syncthreads();
#pragma unroll
    for (int kk = 0; kk < 2; ++kk) {
      bx8 a[4], b[4];
#pragma unroll
      for (int mf = 0; mf < 4; ++mf) {
        const int ra = wr * 64 + mf * 16 + l16;
        const int bc = kk * 64 + lg * 16;
        a[mf] = *reinterpret_cast<const bx8*>(&As[ra * 64 + ((bc ^ ((ra & 7) << 4)) >> 1)]);
      }
#pragma unroll
      for (int nf = 0; nf < 4; ++nf) {
        const int rb_ = wc * 64 + nf * 16 + l16;
        const int bc = kk * 64 + lg * 16;
        b[nf] = *reinterpret_cast<const bx8*>(&Bs[rb_ * 64 + ((bc ^ ((rb_ & 7) << 4)) >> 1)]);
      }
#pragma unroll
      for (int mf = 0; mf < 4; ++mf)
#pragma unroll
        for (int nf = 0; nf < 4; ++nf)
          acc[mf][nf] = mfma16(a[mf], b[nf], acc[mf][nf]);
    }
  }

#pragma unroll
  for (int mf = 0; mf < 4; ++mf)
#pragma unroll
    for (int nf = 0; nf < 4; ++nf)
#pragma unroll
      for (int r = 0; r < 4; ++r) {
        const long row = mb + wr * 64 + mf * 16 + lg * 4 + r;
        const long col = nb + wc * 64 + nf * 16 + l16;
        if (F32OUT)
          ((float*)Cp)[row * N + col] = acc[mf][nf][r];
        else
          ((unsigned short*)Cp)[row * N + col] = f2bf(acc[mf][nf][r]);
      }
}

// ---------- flash attention (causal), split-kv (R7-proven, unchanged) ----------
__global__ __launch_bounds__(256) void fa_kernel(const unsigned short* __restrict__ qkv,
                                                 unsigned short* __restrict__ out,
                                                 unsigned short* __restrict__ Obuf,
                                                 float* __restrict__ ML) {
  __shared__ alignas(16) unsigned short Ks[64 * 136];
  __shared__ alignas(16) unsigned short Vt[128 * 72];
  __shared__ alignas(16) unsigned short Ps[4][16 * 72];

  const int id = blockIdx.x;
  int h, qt, t0, t1;
  bool partial;
  if (id < 512) {
    const int p = id >> 1, c = id & 1;
    qt = 31 - (p >> 4); h = p & 15;
    const int nt0 = (qt + 2) >> 1;
    t0 = c ? nt0 : 0;
    t1 = c ? (qt + 1) : nt0;
    partial = true;
  } else {
    const int s = id - 512;
    qt = 15 - (s >> 4); h = s & 15;
    t0 = 0; t1 = qt + 1;
    partial = false;
  }
  const int qb = qt * 64;

  const int tid = threadIdx.x;
  const int w = tid >> 6, l = tid & 63;
  const int l16 = l & 15, lg = l >> 4;
  const fx4 fz = {0.f, 0.f, 0.f, 0.f};

  const int kr = tid >> 4, kc8 = (tid & 15) * 8;
  const int kv = tid & 63, d0v = (tid >> 6) * 32;

  bx8 qf[4];
  {
    const long qrow = qb + w * 16 + l16;
    const unsigned short* qp = qkv + qrow * 6144L + h * 128 + lg * 8;
#pragma unroll
    for (int kc = 0; kc < 4; ++kc)
      qf[kc] = *reinterpret_cast<const bx8*>(qp + kc * 32);
  }

  fx4 o_acc[8];
#pragma unroll
  for (int i = 0; i < 8; ++i) o_acc[i] = fz;
  float m_r[4] = {-3e38f, -3e38f, -3e38f, -3e38f};
  float l_r[4] = {0.f, 0.f, 0.f, 0.f};

  us8 rK[4], rV[4];
  {
    const long kvb = (long)t0 * 64;
#pragma unroll
    for (int p = 0; p < 4; ++p)
      rK[p] = *reinterpret_cast<const us8*>(qkv + (kvb + p * 16 + kr) * 6144L + 2048 + h * 128 + kc8);
#pragma unroll
    for (int i = 0; i < 4; ++i)
      rV[i] = *reinterpret_cast<const us8*>(qkv + (kvb + kv) * 6144L + 4096 + h * 128 + d0v + i * 8);
  }

  for (int t = t0; t < t1; ++t) {
    __syncthreads();

#pragma unroll
    for (int p = 0; p < 4; ++p)
      *reinterpret_cast<us8*>(&Ks[(p * 16 + kr) * 136 + kc8]) = rK[p];
#pragma unroll
    for (int i = 0; i < 4; ++i)
#pragma unroll
      for (int j = 0; j < 8; ++j)
        Vt[(d0v + i * 8 + j) * 72 + kv] = rV[i][j];

    if (t + 1 < t1) {
      const long kvb = (long)(t + 1) * 64;
#pragma unroll
      for (int p = 0; p < 4; ++p)
        rK[p] = *reinterpret_cast<const us8*>(qkv + (kvb + p * 16 + kr) * 6144L + 2048 + h * 128 + kc8);
#pragma unroll
      for (int i = 0; i < 4; ++i)
        rV[i] = *reinterpret_cast<const us8*>(qkv + (kvb + kv) * 6144L + 4096 + h * 128 + d0v + i * 8);
    }
    __syncthreads();

    fx4 s[4];
#pragma unroll
    for (int nf = 0; nf < 4; ++nf) s[nf] = fz;
#pragma unroll
    for (int kc = 0; kc < 4; ++kc) {
#pragma unroll
      for (int nf = 0; nf < 4; ++nf) {
        const int rl = nf * 16 + l16;
        bx8 kb = *reinterpret_cast<const bx8*>(&Ks[rl * 136 + kc * 32 + lg * 8]);
        s[nf] = mfma16(qf[kc], kb, s[nf]);
      }
    }

    if (t == qt) {
#pragma unroll
      for (int nf = 0; nf < 4; ++nf) {
        const int kv_abs = t * 64 + nf * 16 + l16;
#pragma unroll
        for (int r = 0; r < 4; ++r) {
          const int q_abs = qb + w * 16 + lg * 4 + r;
          if (kv_abs > q_abs) s[nf][r] = -3e38f;
        }
      }
    }

    const float sc2 = 0.1275173831f;  // (1/sqrt(128)) * log2(e)
    float pv[4][4];
#pragma unroll
    for (int r = 0; r < 4; ++r) {
      float rm = fmaxf(fmaxf(s[0][r], s[1][r]), fmaxf(s[2][r], s[3][r]));
      rm = rowmax16(rm);
      const float mn = fmaxf(m_r[r], rm);
      const float fac = exp2f((m_r[r] - mn) * sc2);
      m_r[r] = mn;
      float rs = 0.f;
#pragma unroll
      for (int nf = 0; nf < 4; ++nf) {
        const float p = exp2f((s[nf][r] - mn) * sc2);
        pv[nf][r] = p;
        rs += p;
      }
      rs = rowsum16(rs);
      l_r[r] = l_r[r] * fac + rs;
#pragma unroll
      for (int nf = 0; nf < 8; ++nf) o_acc[nf][r] *= fac;
    }

    unsigned short* psw = &Ps[w][0];
#pragma unroll
    for (int nf = 0; nf < 4; ++nf)
#pragma unroll
      for (int r = 0; r < 4; ++r)
        psw[(lg * 4 + r) * 72 + nf * 16 + l16] = f2bf(pv[nf][r]);

    bx8 pa[2];
#pragma unroll
    for (int kc = 0; kc < 2; ++kc)
      pa[kc] = *reinterpret_cast<const bx8*>(&psw[l16 * 72 + kc * 32 + lg * 8]);

#pragma unroll
    for (int nf = 0; nf < 8; ++nf) {
#pragma unroll
      for (int kc = 0; kc < 2; ++kc) {
        bx8 vb = *reinterpret_cast<const bx8*>(&Vt[(nf * 16 + l16) * 72 + kc * 32 + lg * 8]);
        o_acc[nf] = mfma16(pa[kc], vb, o_acc[nf]);
      }
    }
  }

  if (!partial) {
#pragma unroll
    for (int nf = 0; nf < 8; ++nf)
#pragma unroll
      for (int r = 0; r < 4; ++r) {
        const long row = qb + w * 16 + lg * 4 + r;
        const long col = h * 128 + nf * 16 + l16;
        out[row * 2048 + col] = f2bf(o_acc[nf][r] / l_r[r]);
      }
  } else {
    unsigned short* ob = Obuf + (long)id * 8192;
#pragma unroll
    for (int nf = 0; nf < 8; ++nf)
#pragma unroll
      for (int r = 0; r < 4; ++r) {
        const int row = w * 16 + lg * 4 + r;
        ob[row * 128 + nf * 16 + l16] = f2bf(o_acc[nf][r]);
      }
    if (l16 == 0) {
#pragma unroll
      for (int r = 0; r < 4; ++r) {
        const int row = w * 16 + lg * 4 + r;
        ML[((long)id * 64 + row) * 2 + 0] = m_r[r];
        ML[((long)id * 64 + row) * 2 + 1] = l_r[r];
      }
    }
  }
}

// ---------- combine two kv-chunk partials (R7-proven, unchanged) ----------
__global__ __launch_bounds__(256) void fa_combine(const unsigned short* __restrict__ Obuf,
                                                  const float* __restrict__ ML,
                                                  unsigned short* __restrict__ out) {
  const int p = blockIdx.x;
  const int qt = 31 - (p >> 4), h = p & 15;
  const int tid = threadIdx.x;
  const int row = tid >> 2;
  const int c0 = (tid & 3) * 32;

  const long idA = 2 * p, idB = 2 * p + 1;
  const float mA = ML[(idA * 64 + row) * 2 + 0];
  const float lA = ML[(idA * 64 + row) * 2 + 1];
  const float mB = ML[(idB * 64 + row) * 2 + 0];
  const float lB = ML[(idB * 64 + row) * 2 + 1];
  const float sc2 = 0.1275173831f;
  const float m = fmaxf(mA, mB);
  const float fA = exp2f((mA - m) * sc2);
  const float fB = exp2f((mB - m) * sc2);
  const float inv = 1.0f / (lA * fA + lB * fB);
  const float cA = fA * inv, cB = fB * inv;

  const unsigned short* oa = Obuf + idA * 8192 + row * 128 + c0;
  const unsigned short* obp = Obuf + idB * 8192 + row * 128 + c0;
  unsigned short* dst = out + (long)(qt * 64 + row) * 2048 + h * 128 + c0;
#pragma unroll
  for (int j = 0; j < 4; ++j) {
    us8 a = *reinterpret_cast<const us8*>(oa + j * 8);
    us8 b = *reinterpret_cast<const us8*>(obp + j * 8);
    ushort4 o0, o1;
    float v0, v1, v2, v3;
    v0 = bf2f(a[0]) * cA + bf2f(b[0]) * cB;
    v1 = bf2f(a[1]) * cA + bf2f(b[1]) * cB;
    v2 = bf2f(a[2]) * cA + bf2f(b[2]) * cB;
    v3 = bf2f(a[3]) * cA + bf2f(b[3]) * cB;
    o0 = {f2bf(v0), f2bf(v1), f2bf(v2), f2bf(v3)};
    v0 = bf2f(a[4]) * cA + bf2f(b[4]) * cB;
    v1 = bf2f(a[5]) * cA + bf2f(b[5]) * cB;
    v2 = bf2f(a[6]) * cA + bf2f(b[6]) * cB;
    v3 = bf2f(a[7]) * cA + bf2f(b[7]) * cB;
    o1 = {f2bf(v0), f2bf(v1), f2bf(v2), f2bf(v3)};
    *reinterpret_cast<ushort4*>(dst + j * 8) = o0;
    *reinterpret_cast<ushort4*>(dst + j * 8 + 4) = o1;
  }
}

// ---------- launch ----------
// Interface (confirmed R4): inputs fp32, output fp32.
// Workspace plan (peak 56 MiB):
//   wab   [0, 24 MiB)     bf16 W_attn (dead after GEMM1)
//   qkvb  [24, 48 MiB)    bf16 qkv
//   xb    [48, 56 MiB)    bf16 x (dead after GEMM1)
//   -- after GEMM1, overlaying dead regions:
//   Obuf  [0, 8 MiB)      512 x 64x128 bf16 partial O numerators
//   ML    [8, 8.25 MiB)   512 x 64 x (m,l) fp32
//   attnb [48, 56 MiB)    bf16 attn out (overlays dead xb)
// GEMM2 B = W_proj fp32 folded in staging (no convert needed).
extern "C" void kernel_launch(void* const* d_in, const int* in_sizes, int n_in,
                              void* d_out, int out_size, void* d_ws, size_t ws_size,
                              hipStream_t stream) {
  const float* x  = (const float*)d_in[0];   // (2048, 2048) fp32
  const float* Wa = (const float*)d_in[1];   // (6144, 2048) fp32
  const float* Wp = (const float*)d_in[2];   // (2048, 2048) fp32
  float* out = (float*)d_out;                // (2048, 2048) fp32
  char* ws = (char*)d_ws;

  unsigned short* wab   = (unsigned short*)(ws);                 // 24 MiB
  unsigned short* qkvb  = (unsigned short*)(ws + (24ull << 20)); // 24 MiB
  unsigned short* xb    = (unsigned short*)(ws + (48ull << 20)); //  8 MiB
  unsigned short* Obuf  = (unsigned short*)(ws);                 //  8 MiB (after GEMM1)
  float*          ML    = (float*)(ws + (8ull << 20));           // 256 KiB (after GEMM1)
  unsigned short* attnb = (unsigned short*)(ws + (48ull << 20)); //  8 MiB (after GEMM1)

  f2b_kernel<<<4096, 256, 0, stream>>>(x, xb, 2048 * 2048);
  f2b_kernel<<<12288, 256, 0, stream>>>(Wa, wab, 6144 * 2048);

  // qkv = x @ W_attn^T : M=2048, N=6144, K=2048 — deep-pipelined 256^2 kernel
  gemm256<<<dim3(24, 8), 512, 0, stream>>>(xb, wab, qkvb, 2048, 6144, 2048);

  // causal flash attention, split-kv: 768 one-item blocks, all co-resident
  fa_kernel<<<768, 256, 0, stream>>>(qkvb, attnb, Obuf, ML);

  // merge two-chunk partials (qt >= 16)
  fa_combine<<<256, 256, 0, stream>>>(Obuf, ML, attnb);

  // out = attn @ W_proj^T : M=2048, N=2048, K=2048 (A bf16, B fp32 fold, fp32 out)
  gemm_bt<unsigned short, float, true><<<dim3(16, 16), 256, 0, stream>>>(attnb, Wp, (void*)out, 2048, 2048, 2048);
}